// Round 5
// baseline (94.315 us; speedup 1.0000x reference)
//
#include <hip/hip_runtime.h>

#define NG 512
#define NPX 262144
#define BLOCK 256
#define GTILE 4          // Gaussians per SGPR tile (double-buffered)
#define PPT 4            // pixels per thread
#define GSPLIT 8         // Gaussian-loop split across blocks
#define GPB (NG / GSPLIT)    // 64 Gaussians per block
#define QPX (NPX / PPT)      // 65536 pixel stride between a thread's pixels

#if __has_builtin(__builtin_amdgcn_exp2f)
  #define KSCALE 0.72134752044448170368f   /* 0.5 * log2(e) */
  #define EXPNEG(w) __builtin_amdgcn_exp2f(-(w))
#else
  #define KSCALE 0.5f
  #define EXPNEG(w) __expf(-(w))
#endif

// ---------------------------------------------------------------------------
// Prep kernel, 128 blocks x 256 threads:
//   - zeroes out[] with 2 float4 stores per thread (main atomically accumulates)
//   - threads 0..NG-1 additionally fold rotation/scale/mean/alpha into:
//       ga[n] = (p00, p01, -uoff, alpha)   gb[n] = (p11, -voff)
//     k*q = (p00*x + p01*y - uoff)^2 + (p11*y - voff)^2, k = 0.5*log2(e)
// ---------------------------------------------------------------------------
__global__ void gsplat_prep(const float* __restrict__ alphas,
                            const float* __restrict__ means,
                            const float* __restrict__ rotations,
                            const float* __restrict__ scales,
                            float4* __restrict__ ga,
                            float2* __restrict__ gb,
                            float* __restrict__ out)
{
    int gid = blockIdx.x * blockDim.x + threadIdx.x;   // [0, 32768)
    float4 z4 = make_float4(0.f, 0.f, 0.f, 0.f);
    float4* out4 = (float4*)out;
    out4[2 * gid + 0] = z4;
    out4[2 * gid + 1] = z4;          // 32768 * 32 B = 1 MB zeroed
    if (gid >= NG) return;
    int n = gid;

    float rot = rotations[n];
    float sth, cth;
    sincosf(rot, &sth, &cth);
    float s0 = scales[2 * n + 0];
    float s1 = scales[2 * n + 1];
    float r00 = s0 * cth, r01 = -s1 * sth;
    float r10 = s0 * sth, r11 =  s1 * cth;
    float Ar = r00 * r00 + r01 * r01;
    float Br = r00 * r10 + r01 * r11;
    float Dr = r10 * r10 + r11 * r11;
    float det = Ar * Dr - Br * Br;
    float kc00 =  KSCALE * Dr / det;
    float kc01 = -KSCALE * Br / det;
    float p00 = sqrtf(kc00);
    float p01 = kc01 / p00;
    float p11 = sqrtf(KSCALE / Dr);
    float mx = means[2 * n + 0];
    float my = means[2 * n + 1];
    float nuoff = -(p00 * mx + p01 * my);
    float nvoff = -(p11 * my);

    ga[n] = make_float4(p00, p01, nuoff, alphas[n]);
    gb[n] = make_float2(p11, nvoff);
}

// ---------------------------------------------------------------------------
// Main kernel: 2048 blocks = 256 pixel-blocks x 8 Gaussian splits
// (8 blocks/CU -> full 32 waves/CU residency). PPT=4 pixels/thread over
// GPB=64 Gaussians. Constants live in SGPRs (uniform s_load, double-buffered
// GTILE tiles). Pixel-independent addends (a.z, b.y) are materialized to
// VGPR once per Gaussian and shared by all 4 pixels, so every fma reads
// <=1 SGPR. 4 independent exp chains/thread hide trans latency. Partials
// combined via atomicAdd (out pre-zeroed by prep; same-stream ordering).
// ---------------------------------------------------------------------------
__global__ __launch_bounds__(BLOCK, 8)
void gsplat_main(const float* __restrict__ x,
                 const float4* __restrict__ ga,
                 const float2* __restrict__ gb,
                 float* __restrict__ out)
{
    int bid = blockIdx.x;
    int pixblk = bid >> 3;               // [0, 256)
    int gbase  = (bid & 7) * GPB;        // 0,64,...,448

    int tid = pixblk * BLOCK + threadIdx.x;   // [0, 65536)
    float xx[PPT], yy[PPT];
    #pragma unroll
    for (int p = 0; p < PPT; ++p) {
        float2 pv = ((const float2*)x)[tid + p * QPX];
        xx[p] = pv.x; yy[p] = pv.y;
    }

    float acc0[PPT], acc1[PPT];          // per-pixel, split by Gaussian parity
    #pragma unroll
    for (int p = 0; p < PPT; ++p) { acc0[p] = 0.0f; acc1[p] = 0.0f; }

    float4 ca[GTILE]; float2 cb[GTILE];   // current tile (SGPR)
    float4 na[GTILE]; float2 nb[GTILE];   // next tile (prefetch)

    #pragma unroll
    for (int j = 0; j < GTILE; ++j) { ca[j] = ga[gbase + j]; cb[j] = gb[gbase + j]; }

    #define COMPUTE_TILE(A, B)                                                \
        _Pragma("unroll")                                                     \
        for (int j = 0; j < GTILE; ++j) {                                     \
            float czu = A[j].z;   /* shared s->v materialization */           \
            float czv = B[j].y;                                               \
            _Pragma("unroll")                                                 \
            for (int p = 0; p < PPT; ++p) {                                   \
                float u = fmaf(A[j].x, xx[p], fmaf(A[j].y, yy[p], czu));      \
                float v = fmaf(B[j].x, yy[p], czv);                           \
                float w = fmaf(v, v, u * u);                                  \
                float e = EXPNEG(w);                                          \
                if (j & 1) acc1[p] = fmaf(A[j].w, e, acc1[p]);                \
                else       acc0[p] = fmaf(A[j].w, e, acc0[p]);                \
            }                                                                 \
        }

    for (int t = 0; t < GPB; t += 2 * GTILE) {
        // prefetch tile t+GTILE while computing tile t
        #pragma unroll
        for (int j = 0; j < GTILE; ++j) {
            int n = gbase + ((t + GTILE + j) & (GPB - 1));
            na[j] = ga[n]; nb[j] = gb[n];
        }
        COMPUTE_TILE(ca, cb)

        // prefetch tile t+2*GTILE while computing tile t+GTILE
        #pragma unroll
        for (int j = 0; j < GTILE; ++j) {
            int n = gbase + ((t + 2 * GTILE + j) & (GPB - 1));
            ca[j] = ga[n]; cb[j] = gb[n];
        }
        COMPUTE_TILE(na, nb)
    }
    #undef COMPUTE_TILE

    #pragma unroll
    for (int p = 0; p < PPT; ++p)
        atomicAdd(&out[tid + p * QPX], acc0[p] + acc1[p]);
}

extern "C" void kernel_launch(void* const* d_in, const int* in_sizes, int n_in,
                              void* d_out, int out_size, void* d_ws, size_t ws_size,
                              hipStream_t stream) {
    const float* x         = (const float*)d_in[0];
    const float* alphas    = (const float*)d_in[1];
    const float* means     = (const float*)d_in[2];
    const float* rotations = (const float*)d_in[3];
    const float* scales    = (const float*)d_in[4];
    float* out = (float*)d_out;

    float4* ga = (float4*)d_ws;                          // 512 * 16 B = 8 KB
    float2* gb = (float2*)((char*)d_ws + NG * 16);       // 512 *  8 B = 4 KB

    // zero out[] (float4-wide) + build per-Gaussian constants: 128 blocks
    gsplat_prep<<<NPX / (BLOCK * 8), BLOCK, 0, stream>>>(alphas, means, rotations, scales, ga, gb, out);

    // 2048 blocks = 8 blocks/CU -> 32 waves/CU (full residency, 8 waves/SIMD)
    int grid = (NPX / (BLOCK * PPT)) * GSPLIT;
    gsplat_main<<<grid, BLOCK, 0, stream>>>(x, ga, gb, out);
}